// Round 9
// baseline (199.038 us; speedup 1.0000x reference)
//
#include <hip/hip_runtime.h>
#include <stdint.h>

// Problem constants
#define BB      131072
#define TT      100
#define DT_C    0.01f
#define GAMMA_C 0.05f
#define I0_C    0.12f

typedef short bf16x8 __attribute__((ext_vector_type(8)));
typedef float f32x4  __attribute__((ext_vector_type(4)));

// ws layout: 38 B-fragments (bf16 as u16). Bias folded in as extra K-row
// (k=100 for L0, k=50 for L1/L2, paired with activation 1.0). W2,b2 pre-scaled by dt.
// Fragment = 1024 B; lane L holds B[k=kc*32+(L>>4)*8+j][n=nt*16+(L&15)], j=0..7.
#define F0_U16  0           // L0: 16 frags (kc 0..3, nt 0..3), K=100+bias->128, N=50->64
#define F1_U16  (16*512)    // L1: 8 frags  (kc 0..1, nt 0..3), K=50+bias->64,  N=50->64
#define F2_U16  (24*512)    // L2: 14 frags (kc 0..1, nt 0..6), K=50+bias->64,  N=99->112
#define NFRAG_U16 (38*512)  // 19456 u16 = 38,912 B

__device__ __forceinline__ uint16_t f2bf(float x) {
    uint32_t u = __builtin_bit_cast(uint32_t, x);
    return (uint16_t)((u + 0x7fffu + ((u >> 16) & 1u)) >> 16);   // RTNE (pack kernel only)
}

// Packed f32x2 -> bf16x2 in a u32 (lo = a, hi = b): single HW instruction, RTNE.
__device__ __forceinline__ uint32_t pk2(float a, float b) {
    uint32_t r;
    asm("v_cvt_pk_bf16_f32 %0, %1, %2" : "=v"(r) : "v"(a), "v"(b));
    return r;
}

__global__ void pack_kernel(const float* __restrict__ W0, const float* __restrict__ b0,
                            const float* __restrict__ W1, const float* __restrict__ b1,
                            const float* __restrict__ W2, const float* __restrict__ b2,
                            uint16_t* __restrict__ wsu)
{
    const int gid = blockIdx.x * blockDim.x + threadIdx.x;
    const int gsz = gridDim.x * blockDim.x;
    for (int idx = gid; idx < NFRAG_U16; idx += gsz) {
        int f = idx >> 9;
        int r = idx & 511;
        int L = r >> 3, j = r & 7;
        int k8 = ((L >> 4) << 3) + j;
        int n16 = L & 15;
        float v = 0.0f;
        if (f < 16) {                    // B0[k][n]: W0[n][k] for k<100; b0[n] at k==100
            int kc = f >> 2, nt = f & 3;
            int kk = kc * 32 + k8, nn = nt * 16 + n16;
            if (nn < 50) {
                if (kk < 100) v = W0[nn * 100 + kk];
                else if (kk == 100) v = b0[nn];
            }
        } else if (f < 24) {             // B1[k][n]: W1[n][k] for k<50; b1[n] at k==50
            int g = f - 16; int kc = g >> 2, nt = g & 3;
            int kk = kc * 32 + k8, nn = nt * 16 + n16;
            if (nn < 50) {
                if (kk < 50) v = W1[nn * 50 + kk];
                else if (kk == 50) v = b1[nn];
            }
        } else {                         // B2[k][t]: dt*W2[t][k] for k<50; dt*b2[t] at k==50
            int g = f - 24; int kc = g / 7, nt = g % 7;
            int kk = kc * 32 + k8, nn = nt * 16 + n16;
            if (nn < 99) {
                if (kk < 50) v = DT_C * W2[nn * 50 + kk];
                else if (kk == 50) v = DT_C * b2[nn];
            }
        }
        wsu[idx] = f2bf(v);
    }
}

// Per-wave LDS slab (wave-private -> NO barriers anywhere; same-wave DS ops are
// in-order, which makes the h0/h1/O overlays and tile reuse safe):
//   h0: u16 [32 m][88 n]   at +0 B       (5632 B)
//   h1: u16 [32 m][88 n]   at +5632 B    (5632 B)
//   O:  f32 [32 m][100 t]  at +0 B       (12800 B), overlays h0/h1 after a2 is read.
// The scan consumes O from LDS but writes I directly to GLOBAL (no LDS write-back,
// no burst-store re-read): removes 38 of ~212 LDS instructions per tile from the
// CU's serialized LDS pipe.
#define SLAB_F 3200   // 32*100 floats = 12800 B per wave

// ---- x-tile load: issue 14 (or 12) dwordx4 loads for 32 rows ----
__device__ __forceinline__ void load_x_tile(const float* __restrict__ x, int row0,
                                            int quad, int l15, f32x4 (&xr)[2][7]) {
    #pragma unroll
    for (int h = 0; h < 2; ++h) {
        const float* xrow = x + (size_t)(row0 + h * 16 + l15) * 100;
        #pragma unroll
        for (int kc = 0; kc < 3; ++kc) {
            xr[h][2 * kc]     = *(const f32x4*)(xrow + kc * 32 + quad * 8);
            xr[h][2 * kc + 1] = *(const f32x4*)(xrow + kc * 32 + quad * 8 + 4);
        }
        if (quad == 0) xr[h][6] = *(const f32x4*)(xrow + 96);
        else           xr[h][6] = (f32x4){0.f, 0.f, 0.f, 0.f};
    }
}

// ---- f32 x-regs -> bf16 A0 fragments ----
__device__ __forceinline__ void convert_x(const f32x4 (&xr)[2][7], int quad,
                                          bf16x8 (&a0)[2][4]) {
    #pragma unroll
    for (int h = 0; h < 2; ++h) {
        #pragma unroll
        for (int kc = 0; kc < 3; ++kc) {
            f32x4 p = xr[h][2 * kc], q = xr[h][2 * kc + 1];
            union { bf16x8 v; uint32_t u[4]; } t;
            t.u[0] = pk2(p[0], p[1]); t.u[1] = pk2(p[2], p[3]);
            t.u[2] = pk2(q[0], q[1]); t.u[3] = pk2(q[2], q[3]);
            a0[h][kc] = t.v;
        }
        union { bf16x8 v; uint32_t u[4]; } t;
        t.u[0] = t.u[1] = t.u[2] = t.u[3] = 0u;
        if (quad == 0) {                       // k 96..99 from x; k=100 = bias activation 1.0
            f32x4 p = xr[h][6];
            t.u[0] = pk2(p[0], p[1]); t.u[1] = pk2(p[2], p[3]);
            t.u[2] = 0x00003f80u;              // bf16(1.0) in low half (k=100)
        }
        a0[h][3] = t.v;
    }
}

// ---- full per-tile pipeline after A0: L0 -> L1 -> L2 -> scan+direct store ----
__device__ __forceinline__ void process_tile(const bf16x8 (&a0)[2][4],
                                             const uint16_t* __restrict__ wsu,
                                             float* __restrict__ slabF,
                                             float* __restrict__ out, int row0,
                                             int lane, int quad, int l15) {
    uint16_t* h0u = (uint16_t*)slabF;
    uint16_t* h1u = (uint16_t*)slabF + 32 * 88;
    const bool is50 = (l15 == 2);

    // ===== Layer 0: C0[32,64] = x~[32,128] * B0[128,64] =====
    f32x4 acc0[2][4];
    #pragma unroll
    for (int h = 0; h < 2; ++h)
        #pragma unroll
        for (int nt = 0; nt < 4; ++nt) acc0[h][nt] = (f32x4){0.f, 0.f, 0.f, 0.f};
    #pragma unroll
    for (int kc = 0; kc < 4; ++kc) {
        #pragma unroll
        for (int nt = 0; nt < 4; ++nt) {
            bf16x8 b = ((const bf16x8*)(wsu + F0_U16 + (kc * 4 + nt) * 512))[lane];
            acc0[0][nt] = __builtin_amdgcn_mfma_f32_16x16x32_bf16(a0[0][kc], b, acc0[0][nt], 0, 0, 0);
            acc0[1][nt] = __builtin_amdgcn_mfma_f32_16x16x32_bf16(a0[1][kc], b, acc0[1][nt], 0, 0, 0);
        }
    }
    #pragma unroll
    for (int h = 0; h < 2; ++h) {
        #pragma unroll
        for (int nt = 0; nt < 4; ++nt) {
            const int n = nt * 16 + l15;
            #pragma unroll
            for (int r2 = 0; r2 < 4; r2 += 2) {
                float v0 = fmaxf(acc0[h][nt][r2], 0.0f);
                float v1 = fmaxf(acc0[h][nt][r2 + 1], 0.0f);
                if (nt == 3 && is50) { v0 = 1.0f; v1 = 1.0f; }
                uint32_t p = pk2(v0, v1);
                const int m = h * 16 + quad * 4 + r2;
                h0u[m * 88 + n]       = (uint16_t)p;
                h0u[(m + 1) * 88 + n] = (uint16_t)(p >> 16);
            }
        }
    }

    // ===== Layer 1: C1[32,64] = h0[32,64] * B1[64,64] =====
    bf16x8 a1[2][2];
    #pragma unroll
    for (int h = 0; h < 2; ++h)
        #pragma unroll
        for (int kc = 0; kc < 2; ++kc)
            a1[h][kc] = *(const bf16x8*)(h0u + (h * 16 + l15) * 88 + kc * 32 + quad * 8);

    f32x4 acc1[2][4];
    #pragma unroll
    for (int h = 0; h < 2; ++h)
        #pragma unroll
        for (int nt = 0; nt < 4; ++nt) acc1[h][nt] = (f32x4){0.f, 0.f, 0.f, 0.f};
    #pragma unroll
    for (int kc = 0; kc < 2; ++kc) {
        #pragma unroll
        for (int nt = 0; nt < 4; ++nt) {
            bf16x8 b = ((const bf16x8*)(wsu + F1_U16 + (kc * 4 + nt) * 512))[lane];
            acc1[0][nt] = __builtin_amdgcn_mfma_f32_16x16x32_bf16(a1[0][kc], b, acc1[0][nt], 0, 0, 0);
            acc1[1][nt] = __builtin_amdgcn_mfma_f32_16x16x32_bf16(a1[1][kc], b, acc1[1][nt], 0, 0, 0);
        }
    }
    #pragma unroll
    for (int h = 0; h < 2; ++h) {
        #pragma unroll
        for (int nt = 0; nt < 4; ++nt) {
            const int n = nt * 16 + l15;
            #pragma unroll
            for (int r2 = 0; r2 < 4; r2 += 2) {
                float v0 = fmaxf(acc1[h][nt][r2], 0.0f);
                float v1 = fmaxf(acc1[h][nt][r2 + 1], 0.0f);
                if (nt == 3 && is50) { v0 = 1.0f; v1 = 1.0f; }
                uint32_t p = pk2(v0, v1);
                const int m = h * 16 + quad * 4 + r2;
                h1u[m * 88 + n]       = (uint16_t)p;
                h1u[(m + 1) * 88 + n] = (uint16_t)(p >> 16);
            }
        }
    }

    // ===== Layer 2: O[32,112] = h1[32,64] * B2[64,112] (dt, bias folded) =====
    bf16x8 a2[2][2];
    #pragma unroll
    for (int h = 0; h < 2; ++h)
        #pragma unroll
        for (int kc = 0; kc < 2; ++kc)
            a2[h][kc] = *(const bf16x8*)(h1u + (h * 16 + l15) * 88 + kc * 32 + quad * 8);

    // group A: nt 0..3
    {
        f32x4 acc2[2][4];
        #pragma unroll
        for (int h = 0; h < 2; ++h)
            #pragma unroll
            for (int nt = 0; nt < 4; ++nt) acc2[h][nt] = (f32x4){0.f, 0.f, 0.f, 0.f};
        #pragma unroll
        for (int kc = 0; kc < 2; ++kc) {
            #pragma unroll
            for (int nt = 0; nt < 4; ++nt) {
                bf16x8 b = ((const bf16x8*)(wsu + F2_U16 + (kc * 7 + nt) * 512))[lane];
                acc2[0][nt] = __builtin_amdgcn_mfma_f32_16x16x32_bf16(a2[0][kc], b, acc2[0][nt], 0, 0, 0);
                acc2[1][nt] = __builtin_amdgcn_mfma_f32_16x16x32_bf16(a2[1][kc], b, acc2[1][nt], 0, 0, 0);
            }
        }
        #pragma unroll
        for (int h = 0; h < 2; ++h)
            #pragma unroll
            for (int nt = 0; nt < 4; ++nt) {
                const int t = nt * 16 + l15;
                #pragma unroll
                for (int r = 0; r < 4; ++r)
                    slabF[(h * 16 + quad * 4 + r) * 100 + t] = acc2[h][nt][r];
            }
    }
    // group B: nt 4..6 (nt==6 masked to t<=98)
    {
        f32x4 acc2[2][3];
        #pragma unroll
        for (int h = 0; h < 2; ++h)
            #pragma unroll
            for (int nt = 0; nt < 3; ++nt) acc2[h][nt] = (f32x4){0.f, 0.f, 0.f, 0.f};
        #pragma unroll
        for (int kc = 0; kc < 2; ++kc) {
            #pragma unroll
            for (int nt = 0; nt < 3; ++nt) {
                bf16x8 b = ((const bf16x8*)(wsu + F2_U16 + (kc * 7 + (nt + 4)) * 512))[lane];
                acc2[0][nt] = __builtin_amdgcn_mfma_f32_16x16x32_bf16(a2[0][kc], b, acc2[0][nt], 0, 0, 0);
                acc2[1][nt] = __builtin_amdgcn_mfma_f32_16x16x32_bf16(a2[1][kc], b, acc2[1][nt], 0, 0, 0);
            }
        }
        #pragma unroll
        for (int h = 0; h < 2; ++h)
            #pragma unroll
            for (int nt = 0; nt < 3; ++nt) {
                const int t = (nt + 4) * 16 + l15;
                if (nt < 2 || l15 < 3) {
                    #pragma unroll
                    for (int r = 0; r < 4; ++r)
                        slabF[(h * 16 + quad * 4 + r) * 100 + t] = acc2[h][nt][r];
                }
            }
    }

    // ===== Euler scan + DIRECT global store: lane m scans row m (lanes 0..31) =====
    // I_new = I * (c + op - op*I); I-values stream straight from registers to
    // global (per-lane contiguous 16B chunks; L2 write-combines full lines).
    if (lane < 32) {
        float* orow = slabF + lane * 100;
        float* grow = out + (size_t)(row0 + lane) * 100;
        const float c = 1.0f - DT_C * GAMMA_C;
        float prev = I0_C;
        #pragma unroll
        for (int ch = 0; ch < 5; ++ch) {
            f32x4 rb[5];
            #pragma unroll
            for (int v = 0; v < 5; ++v)
                rb[v] = *(const f32x4*)(orow + ch * 20 + v * 4);
            float ob[20];
            #pragma unroll
            for (int j = 0; j < 20; ++j) {
                ob[j] = prev;                         // I[ch*20+j]
                if (ch * 20 + j <= 98) {              // o'[99] slot is stale/unused
                    const float op = rb[j >> 2][j & 3];
                    prev = prev * fmaf(-op, prev, c + op);
                }
            }
            #pragma unroll
            for (int v = 0; v < 5; ++v) {
                f32x4 w = { ob[v * 4], ob[v * 4 + 1], ob[v * 4 + 2], ob[v * 4 + 3] };
                __builtin_nontemporal_store(w, (f32x4*)(grow + ch * 20 + v * 4));
            }
        }
    }
}

// 2 tiles per wave, software-pipelined: tile1's x-loads are issued BEFORE tile0's
// compute/scan/store, so their ~900-cycle HBM latency hides under tile0's work,
// and tile0's store drain overlaps tile1's compute (confirmed: R8 -3.7 us).
__global__ __launch_bounds__(256, 3) void net_kernel(
    const float* __restrict__ x,
    const void*  __restrict__ wsv,
    float* __restrict__ out)
{
    __shared__ float lds[4 * SLAB_F];    // 51,200 B
    const int tid  = threadIdx.x;
    const int wave = tid >> 6, lane = tid & 63;
    const int quad = lane >> 4, l15 = lane & 15;
    float* slabF = lds + wave * SLAB_F;
    const uint16_t* wsu = (const uint16_t*)wsv;

    const int base = (blockIdx.x * 4 + wave) * 64;   // this wave's 64 batch rows (2 tiles)

    f32x4 xr[2][7];
    bf16x8 a0t0[2][4], a0t1[2][4];

    load_x_tile(x, base, quad, l15, xr);             // tile0 loads
    convert_x(xr, quad, a0t0);                       // waits + converts (f32 regs die here)
    load_x_tile(x, base + 32, quad, l15, xr);        // tile1 loads issued EARLY
    process_tile(a0t0, wsu, slabF, out, base, lane, quad, l15);       // hides tile1 latency
    convert_x(xr, quad, a0t1);
    process_tile(a0t1, wsu, slabF, out, base + 32, lane, quad, l15);
}

extern "C" void kernel_launch(void* const* d_in, const int* in_sizes, int n_in,
                              void* d_out, int out_size, void* d_ws, size_t ws_size,
                              hipStream_t stream) {
    const float* x  = (const float*)d_in[0];
    const float* W0 = (const float*)d_in[1];
    const float* b0 = (const float*)d_in[2];
    const float* W1 = (const float*)d_in[3];
    const float* b1 = (const float*)d_in[4];
    const float* W2 = (const float*)d_in[5];
    const float* b2 = (const float*)d_in[6];
    float* out = (float*)d_out;
    uint16_t* wsu = (uint16_t*)d_ws;

    pack_kernel<<<dim3(80), dim3(256), 0, stream>>>(W0, b0, W1, b1, W2, b2, wsu);
    net_kernel<<<dim3(BB / 256), dim3(256), 0, stream>>>(x, (const void*)wsu, out);
}

// Round 10
// 117.710 us; speedup vs baseline: 1.6909x; 1.6909x over previous
//
#include <hip/hip_runtime.h>
#include <stdint.h>

// Problem constants
#define BB      131072
#define TT      100
#define DT_C    0.01f
#define GAMMA_C 0.05f
#define I0_C    0.12f

typedef short bf16x8 __attribute__((ext_vector_type(8)));
typedef float f32x4  __attribute__((ext_vector_type(4)));

// ws layout: 38 B-fragments (bf16 as u16). Bias folded in as extra K-row
// (k=100 for L0, k=50 for L1/L2, paired with activation 1.0). W2,b2 pre-scaled by dt.
// Fragment = 1024 B; lane L holds B[k=kc*32+(L>>4)*8+j][n=nt*16+(L&15)], j=0..7.
#define F0_U16  0           // L0: 16 frags (kc 0..3, nt 0..3), K=100+bias->128, N=50->64
#define F1_U16  (16*512)    // L1: 8 frags  (kc 0..1, nt 0..3), K=50+bias->64,  N=50->64
#define F2_U16  (24*512)    // L2: 14 frags (kc 0..1, nt 0..6), K=50+bias->64,  N=99->112
#define NFRAG_U16 (38*512)  // 19456 u16 = 38,912 B

__device__ __forceinline__ uint16_t f2bf(float x) {
    uint32_t u = __builtin_bit_cast(uint32_t, x);
    return (uint16_t)((u + 0x7fffu + ((u >> 16) & 1u)) >> 16);   // RTNE (pack kernel only)
}

// Packed f32x2 -> bf16x2 in a u32 (lo = a, hi = b): single HW instruction, RTNE.
__device__ __forceinline__ uint32_t pk2(float a, float b) {
    uint32_t r;
    asm("v_cvt_pk_bf16_f32 %0, %1, %2" : "=v"(r) : "v"(a), "v"(b));
    return r;
}

__global__ void pack_kernel(const float* __restrict__ W0, const float* __restrict__ b0,
                            const float* __restrict__ W1, const float* __restrict__ b1,
                            const float* __restrict__ W2, const float* __restrict__ b2,
                            uint16_t* __restrict__ wsu)
{
    const int gid = blockIdx.x * blockDim.x + threadIdx.x;
    const int gsz = gridDim.x * blockDim.x;
    for (int idx = gid; idx < NFRAG_U16; idx += gsz) {
        int f = idx >> 9;
        int r = idx & 511;
        int L = r >> 3, j = r & 7;
        int k8 = ((L >> 4) << 3) + j;
        int n16 = L & 15;
        float v = 0.0f;
        if (f < 16) {                    // B0[k][n]: W0[n][k] for k<100; b0[n] at k==100
            int kc = f >> 2, nt = f & 3;
            int kk = kc * 32 + k8, nn = nt * 16 + n16;
            if (nn < 50) {
                if (kk < 100) v = W0[nn * 100 + kk];
                else if (kk == 100) v = b0[nn];
            }
        } else if (f < 24) {             // B1[k][n]: W1[n][k] for k<50; b1[n] at k==50
            int g = f - 16; int kc = g >> 2, nt = g & 3;
            int kk = kc * 32 + k8, nn = nt * 16 + n16;
            if (nn < 50) {
                if (kk < 50) v = W1[nn * 50 + kk];
                else if (kk == 50) v = b1[nn];
            }
        } else {                         // B2[k][t]: dt*W2[t][k] for k<50; dt*b2[t] at k==50
            int g = f - 24; int kc = g / 7, nt = g % 7;
            int kk = kc * 32 + k8, nn = nt * 16 + n16;
            if (nn < 99) {
                if (kk < 50) v = DT_C * W2[nn * 50 + kk];
                else if (kk == 50) v = DT_C * b2[nn];
            }
        }
        wsu[idx] = f2bf(v);
    }
}

// Per-wave LDS slab (wave-private -> NO barriers anywhere; same-wave DS ops are
// in-order, which makes the h0/h1/O overlays and tile reuse safe):
//   h0: u16 [32 m][88 n]   at +0 B       (5632 B)
//   h1: u16 [32 m][88 n]   at +5632 B    (5632 B)
//   O:  f32 [32 m][100 t]  at +0 B       (12800 B), overlays h0/h1 after a2 is read.
// The scan writes I back to LDS and the burst store re-reads it: that LDS
// round-trip is what buys wave-coalesced 1KiB global stores. R9 measured the
// alternative (direct per-lane 16B nontemporal stores): 3.1x write amplification
// (WRITE_SIZE 51.2 -> 160 MB) -- nontemporal partial-line stores bypass L2
// write-combining. Do NOT remove the round-trip.
#define SLAB_F 3200   // 32*100 floats = 12800 B per wave

// ---- x-tile load: issue 14 (or 12) dwordx4 loads for 32 rows ----
__device__ __forceinline__ void load_x_tile(const float* __restrict__ x, int row0,
                                            int quad, int l15, f32x4 (&xr)[2][7]) {
    #pragma unroll
    for (int h = 0; h < 2; ++h) {
        const float* xrow = x + (size_t)(row0 + h * 16 + l15) * 100;
        #pragma unroll
        for (int kc = 0; kc < 3; ++kc) {
            xr[h][2 * kc]     = *(const f32x4*)(xrow + kc * 32 + quad * 8);
            xr[h][2 * kc + 1] = *(const f32x4*)(xrow + kc * 32 + quad * 8 + 4);
        }
        if (quad == 0) xr[h][6] = *(const f32x4*)(xrow + 96);
        else           xr[h][6] = (f32x4){0.f, 0.f, 0.f, 0.f};
    }
}

// ---- f32 x-regs -> bf16 A0 fragments ----
__device__ __forceinline__ void convert_x(const f32x4 (&xr)[2][7], int quad,
                                          bf16x8 (&a0)[2][4]) {
    #pragma unroll
    for (int h = 0; h < 2; ++h) {
        #pragma unroll
        for (int kc = 0; kc < 3; ++kc) {
            f32x4 p = xr[h][2 * kc], q = xr[h][2 * kc + 1];
            union { bf16x8 v; uint32_t u[4]; } t;
            t.u[0] = pk2(p[0], p[1]); t.u[1] = pk2(p[2], p[3]);
            t.u[2] = pk2(q[0], q[1]); t.u[3] = pk2(q[2], q[3]);
            a0[h][kc] = t.v;
        }
        union { bf16x8 v; uint32_t u[4]; } t;
        t.u[0] = t.u[1] = t.u[2] = t.u[3] = 0u;
        if (quad == 0) {                       // k 96..99 from x; k=100 = bias activation 1.0
            f32x4 p = xr[h][6];
            t.u[0] = pk2(p[0], p[1]); t.u[1] = pk2(p[2], p[3]);
            t.u[2] = 0x00003f80u;              // bf16(1.0) in low half (k=100)
        }
        a0[h][3] = t.v;
    }
}

// ---- full per-tile pipeline after A0: L0 -> L1 -> L2 -> scan -> store ----
__device__ __forceinline__ void process_tile(const bf16x8 (&a0)[2][4],
                                             const uint16_t* __restrict__ wsu,
                                             float* __restrict__ slabF,
                                             float* __restrict__ out, int row0,
                                             int lane, int quad, int l15) {
    uint16_t* h0u = (uint16_t*)slabF;
    uint16_t* h1u = (uint16_t*)slabF + 32 * 88;
    const bool is50 = (l15 == 2);

    // ===== Layer 0: C0[32,64] = x~[32,128] * B0[128,64] =====
    f32x4 acc0[2][4];
    #pragma unroll
    for (int h = 0; h < 2; ++h)
        #pragma unroll
        for (int nt = 0; nt < 4; ++nt) acc0[h][nt] = (f32x4){0.f, 0.f, 0.f, 0.f};
    #pragma unroll
    for (int kc = 0; kc < 4; ++kc) {
        #pragma unroll
        for (int nt = 0; nt < 4; ++nt) {
            bf16x8 b = ((const bf16x8*)(wsu + F0_U16 + (kc * 4 + nt) * 512))[lane];
            acc0[0][nt] = __builtin_amdgcn_mfma_f32_16x16x32_bf16(a0[0][kc], b, acc0[0][nt], 0, 0, 0);
            acc0[1][nt] = __builtin_amdgcn_mfma_f32_16x16x32_bf16(a0[1][kc], b, acc0[1][nt], 0, 0, 0);
        }
    }
    #pragma unroll
    for (int h = 0; h < 2; ++h) {
        #pragma unroll
        for (int nt = 0; nt < 4; ++nt) {
            const int n = nt * 16 + l15;
            #pragma unroll
            for (int r2 = 0; r2 < 4; r2 += 2) {
                float v0 = fmaxf(acc0[h][nt][r2], 0.0f);
                float v1 = fmaxf(acc0[h][nt][r2 + 1], 0.0f);
                if (nt == 3 && is50) { v0 = 1.0f; v1 = 1.0f; }
                uint32_t p = pk2(v0, v1);
                const int m = h * 16 + quad * 4 + r2;
                h0u[m * 88 + n]       = (uint16_t)p;
                h0u[(m + 1) * 88 + n] = (uint16_t)(p >> 16);
            }
        }
    }

    // ===== Layer 1: C1[32,64] = h0[32,64] * B1[64,64] =====
    bf16x8 a1[2][2];
    #pragma unroll
    for (int h = 0; h < 2; ++h)
        #pragma unroll
        for (int kc = 0; kc < 2; ++kc)
            a1[h][kc] = *(const bf16x8*)(h0u + (h * 16 + l15) * 88 + kc * 32 + quad * 8);

    f32x4 acc1[2][4];
    #pragma unroll
    for (int h = 0; h < 2; ++h)
        #pragma unroll
        for (int nt = 0; nt < 4; ++nt) acc1[h][nt] = (f32x4){0.f, 0.f, 0.f, 0.f};
    #pragma unroll
    for (int kc = 0; kc < 2; ++kc) {
        #pragma unroll
        for (int nt = 0; nt < 4; ++nt) {
            bf16x8 b = ((const bf16x8*)(wsu + F1_U16 + (kc * 4 + nt) * 512))[lane];
            acc1[0][nt] = __builtin_amdgcn_mfma_f32_16x16x32_bf16(a1[0][kc], b, acc1[0][nt], 0, 0, 0);
            acc1[1][nt] = __builtin_amdgcn_mfma_f32_16x16x32_bf16(a1[1][kc], b, acc1[1][nt], 0, 0, 0);
        }
    }
    #pragma unroll
    for (int h = 0; h < 2; ++h) {
        #pragma unroll
        for (int nt = 0; nt < 4; ++nt) {
            const int n = nt * 16 + l15;
            #pragma unroll
            for (int r2 = 0; r2 < 4; r2 += 2) {
                float v0 = fmaxf(acc1[h][nt][r2], 0.0f);
                float v1 = fmaxf(acc1[h][nt][r2 + 1], 0.0f);
                if (nt == 3 && is50) { v0 = 1.0f; v1 = 1.0f; }
                uint32_t p = pk2(v0, v1);
                const int m = h * 16 + quad * 4 + r2;
                h1u[m * 88 + n]       = (uint16_t)p;
                h1u[(m + 1) * 88 + n] = (uint16_t)(p >> 16);
            }
        }
    }

    // ===== Layer 2: O[32,112] = h1[32,64] * B2[64,112] (dt, bias folded) =====
    bf16x8 a2[2][2];
    #pragma unroll
    for (int h = 0; h < 2; ++h)
        #pragma unroll
        for (int kc = 0; kc < 2; ++kc)
            a2[h][kc] = *(const bf16x8*)(h1u + (h * 16 + l15) * 88 + kc * 32 + quad * 8);

    // group A: nt 0..3
    {
        f32x4 acc2[2][4];
        #pragma unroll
        for (int h = 0; h < 2; ++h)
            #pragma unroll
            for (int nt = 0; nt < 4; ++nt) acc2[h][nt] = (f32x4){0.f, 0.f, 0.f, 0.f};
        #pragma unroll
        for (int kc = 0; kc < 2; ++kc) {
            #pragma unroll
            for (int nt = 0; nt < 4; ++nt) {
                bf16x8 b = ((const bf16x8*)(wsu + F2_U16 + (kc * 7 + nt) * 512))[lane];
                acc2[0][nt] = __builtin_amdgcn_mfma_f32_16x16x32_bf16(a2[0][kc], b, acc2[0][nt], 0, 0, 0);
                acc2[1][nt] = __builtin_amdgcn_mfma_f32_16x16x32_bf16(a2[1][kc], b, acc2[1][nt], 0, 0, 0);
            }
        }
        #pragma unroll
        for (int h = 0; h < 2; ++h)
            #pragma unroll
            for (int nt = 0; nt < 4; ++nt) {
                const int t = nt * 16 + l15;
                #pragma unroll
                for (int r = 0; r < 4; ++r)
                    slabF[(h * 16 + quad * 4 + r) * 100 + t] = acc2[h][nt][r];
            }
    }
    // group B: nt 4..6 (nt==6 masked to t<=98)
    {
        f32x4 acc2[2][3];
        #pragma unroll
        for (int h = 0; h < 2; ++h)
            #pragma unroll
            for (int nt = 0; nt < 3; ++nt) acc2[h][nt] = (f32x4){0.f, 0.f, 0.f, 0.f};
        #pragma unroll
        for (int kc = 0; kc < 2; ++kc) {
            #pragma unroll
            for (int nt = 0; nt < 3; ++nt) {
                bf16x8 b = ((const bf16x8*)(wsu + F2_U16 + (kc * 7 + (nt + 4)) * 512))[lane];
                acc2[0][nt] = __builtin_amdgcn_mfma_f32_16x16x32_bf16(a2[0][kc], b, acc2[0][nt], 0, 0, 0);
                acc2[1][nt] = __builtin_amdgcn_mfma_f32_16x16x32_bf16(a2[1][kc], b, acc2[1][nt], 0, 0, 0);
            }
        }
        #pragma unroll
        for (int h = 0; h < 2; ++h)
            #pragma unroll
            for (int nt = 0; nt < 3; ++nt) {
                const int t = (nt + 4) * 16 + l15;
                if (nt < 2 || l15 < 3) {
                    #pragma unroll
                    for (int r = 0; r < 4; ++r)
                        slabF[(h * 16 + quad * 4 + r) * 100 + t] = acc2[h][nt][r];
                }
            }
    }

    // ===== Euler scan: lane m scans row m (lanes 0..31), vectorized LDS I/O =====
    if (lane < 32) {
        float* orow = slabF + lane * 100;
        const float c = 1.0f - DT_C * GAMMA_C;
        float prev = I0_C;
        #pragma unroll
        for (int ch = 0; ch < 5; ++ch) {
            f32x4 rb[5];
            #pragma unroll
            for (int v = 0; v < 5; ++v)
                rb[v] = *(const f32x4*)(orow + ch * 20 + v * 4);
            float ob[20];
            #pragma unroll
            for (int j = 0; j < 20; ++j) {
                ob[j] = prev;                         // I[ch*20+j]
                if (ch * 20 + j <= 98) {              // o'[99] slot is stale/unused
                    const float op = rb[j >> 2][j & 3];
                    prev = prev * fmaf(-op, prev, c + op);
                }
            }
            #pragma unroll
            for (int v = 0; v < 5; ++v) {
                f32x4 w = { ob[v * 4], ob[v * 4 + 1], ob[v * 4 + 2], ob[v * 4 + 3] };
                *(f32x4*)(orow + ch * 20 + v * 4) = w;
            }
        }
    }

    // ===== Contiguous burst store: slab IS the 32x100 output block =====
    float* gout = out + (size_t)row0 * 100;
    #pragma unroll
    for (int q = 0; q < 13; ++q) {
        const int i = q * 64 + lane;             // float4 index, 800 total
        if (i < 800) {
            f32x4 v = *(const f32x4*)(slabF + 4 * i);
            __builtin_nontemporal_store(v, (f32x4*)(gout + 4 * i));
        }
    }
}

// 2 tiles per wave, software-pipelined: tile1's x-loads are issued BEFORE tile0's
// compute/scan/store, so their ~900-cycle HBM latency hides under tile0's work,
// and tile0's store drain overlaps tile1's compute (confirmed: R8 -3.7 us).
__global__ __launch_bounds__(256, 3) void net_kernel(
    const float* __restrict__ x,
    const void*  __restrict__ wsv,
    float* __restrict__ out)
{
    __shared__ float lds[4 * SLAB_F];    // 51,200 B
    const int tid  = threadIdx.x;
    const int wave = tid >> 6, lane = tid & 63;
    const int quad = lane >> 4, l15 = lane & 15;
    float* slabF = lds + wave * SLAB_F;
    const uint16_t* wsu = (const uint16_t*)wsv;

    const int base = (blockIdx.x * 4 + wave) * 64;   // this wave's 64 batch rows (2 tiles)

    f32x4 xr[2][7];
    bf16x8 a0t0[2][4], a0t1[2][4];

    load_x_tile(x, base, quad, l15, xr);             // tile0 loads
    convert_x(xr, quad, a0t0);                       // waits + converts (f32 regs die here)
    load_x_tile(x, base + 32, quad, l15, xr);        // tile1 loads issued EARLY
    process_tile(a0t0, wsu, slabF, out, base, lane, quad, l15);       // hides tile1 latency
    convert_x(xr, quad, a0t1);
    process_tile(a0t1, wsu, slabF, out, base + 32, lane, quad, l15);
}

extern "C" void kernel_launch(void* const* d_in, const int* in_sizes, int n_in,
                              void* d_out, int out_size, void* d_ws, size_t ws_size,
                              hipStream_t stream) {
    const float* x  = (const float*)d_in[0];
    const float* W0 = (const float*)d_in[1];
    const float* b0 = (const float*)d_in[2];
    const float* W1 = (const float*)d_in[3];
    const float* b1 = (const float*)d_in[4];
    const float* W2 = (const float*)d_in[5];
    const float* b2 = (const float*)d_in[6];
    float* out = (float*)d_out;
    uint16_t* wsu = (uint16_t*)d_ws;

    pack_kernel<<<dim3(80), dim3(256), 0, stream>>>(W0, b0, W1, b1, W2, b2, wsu);
    net_kernel<<<dim3(BB / 256), dim3(256), 0, stream>>>(x, (const void*)wsu, out);
}